// Round 3
// baseline (932.833 us; speedup 1.0000x reference)
//
#include <hip/hip_runtime.h>
#include <math.h>

#define BB 4096
#define LL 200
#define EE 128
#define FF 64
#define NTHREADS 512   // 8 waves; each wave owns 16 output columns (one N-tile)

#define CROWS 32       // M-rows staged per chunk (2 MFMA M-tiles); was 64.
                       // 32-row chunks cut LDS to ~37.6 KB -> 4 blocks/CU (was 2).
#define NCH 7          // ceil(200/32) chunks: 6 full (2 tiles) + 1 tail (1 tile)

// LDS row pitches (bf16 elems). pitch_bytes = 16*odd -> A-operand ds_read_b128
// 16B-column index = (9m+q) mod 8, uniform -> conflict-free.
#define PITCH_F  72     // features K=64  (+8 pad), 144 B = 16*9
#define PITCH_FX 136    // fx       K=128 (+8 pad), 272 B = 16*17
#define PITCH_X3 264    // items|comp K=256 (+8 pad), 528 B = 16*33

typedef __attribute__((ext_vector_type(4))) float  floatx4;
typedef __attribute__((ext_vector_type(8))) short  shortx8;

#define MFMA16(a, b, c) __builtin_amdgcn_mfma_f32_16x16x32_bf16((a), (b), (c), 0, 0, 0)

// HW packed f32->bf16 RTNE: 1 VALU op per 2 elements (the manual bit-trick was
// ~4-5 ops/elem and runs ~100K times per block in staging+epilogues).
__device__ __forceinline__ unsigned cvt_pk_bf16(float lo, float hi) {
    unsigned r;
    asm("v_cvt_pk_bf16_f32 %0, %1, %2" : "=v"(r) : "v"(lo), "v"(hi));
    return r;
}
__device__ __forceinline__ unsigned short f2bf(float f) {
    return (unsigned short)cvt_pk_bf16(f, f);   // src0 lands in low 16 bits
}
__device__ __forceinline__ uint2 pk4(float4 v) {
    uint2 o;
    o.x = cvt_pk_bf16(v.x, v.y);
    o.y = cvt_pk_bf16(v.z, v.w);
    return o;
}

// load 8 consecutive fp32, round to bf16, return MFMA B-fragment
__device__ __forceinline__ shortx8 load_bfrag(const float* p) {
    float4 v0 = ((const float4*)p)[0];
    float4 v1 = ((const float4*)p)[1];
    union { unsigned u[4]; shortx8 s; } r;
    r.u[0] = cvt_pk_bf16(v0.x, v0.y);
    r.u[1] = cvt_pk_bf16(v0.z, v0.w);
    r.u[2] = cvt_pk_bf16(v1.x, v1.y);
    r.u[3] = cvt_pk_bf16(v1.z, v1.w);
    return r.s;
}

__device__ __forceinline__ float waveMax(float v) {
    #pragma unroll
    for (int off = 32; off > 0; off >>= 1)
        v = fmaxf(v, __shfl_xor(v, off, 64));
    return v;
}
__device__ __forceinline__ float waveSum(float v) {
    #pragma unroll
    for (int off = 32; off > 0; off >>= 1)
        v += __shfl_xor(v, off, 64);
    return v;
}

__global__ __launch_bounds__(NTHREADS, 8)   // force VGPR<=64 -> 8 waves/SIMD
void usernet_mfma(const int* __restrict__ user_ids,
                  const int* __restrict__ item_ids,
                  const float* __restrict__ features,
                  const float* __restrict__ user_emb,
                  const float* __restrict__ item_emb,
                  const float* __restrict__ feat_w1,
                  const float* __restrict__ feat_b1,
                  const float* __restrict__ feat_w2,
                  const float* __restrict__ feat_b2,
                  const float* __restrict__ w1,
                  const float* __restrict__ b1,
                  const float* __restrict__ w2,
                  const float* __restrict__ b2,
                  float* __restrict__ out)
{
    // big-3 staging buffers: 4608 + 8704 + 16896 = 30208 B
    __shared__ __align__(16) unsigned short s_feat[CROWS * PITCH_F];
    __shared__ __align__(16) unsigned short s_fx  [CROWS * PITCH_FX];
    __shared__ __align__(16) unsigned short s_x3  [CROWS * PITCH_X3];
    __shared__ float s_user[EE];
    __shared__ float s_bias1[EE];     // u1 + feat_b1
    __shared__ float s_bias2[EE];     // feat_b2
    __shared__ float s_bias3[EE];     // u3 + b1
    __shared__ float s_w2[EE];
    __shared__ float s_lp[8][CROWS];  // per-wave logit partials, current chunk only (1 KB)
    __shared__ float s_logit[208];    // folded logits, all rows
    __shared__ float s_attn[208];
    __shared__ float s_red[12];
    __shared__ float s_part[4][EE];
    // total ~37.6 KB -> 4 blocks/CU

    const int b    = blockIdx.x;
    const int tid  = threadIdx.x;
    const int lane = tid & 63;
    const int wv   = tid >> 6;         // wave id 0..7: owns output cols [16*wv, 16*wv+16)
    const int m    = lane & 15;
    const int q    = lane >> 4;
    const int n0   = wv * 16 + m;      // owned output col for this lane

    // ---- persistent B fragments (56 VGPRs/wave; user cols folded out) ----
    shortx8 B1[2];   // feat_w1 features part, K=64
    shortx8 B2[4];   // feat_w2, K=128
    shortx8 B3[8];   // w1 item|comp part, K=256
    #pragma unroll
    for (int ks = 0; ks < 2; ++ks)
        B1[ks] = load_bfrag(feat_w1 + (size_t)n0 * (EE + FF) + EE + ks * 32 + q * 8);
    #pragma unroll
    for (int ks = 0; ks < 4; ++ks)
        B2[ks] = load_bfrag(feat_w2 + (size_t)n0 * EE + ks * 32 + q * 8);
    #pragma unroll
    for (int ks = 0; ks < 8; ++ks)
        B3[ks] = load_bfrag(w1 + (size_t)n0 * (3 * EE) + EE + ks * 32 + q * 8);

    // ---- user row + small vectors ----
    if (tid < 32) {
        const int uid = user_ids[b];
        ((float4*)s_user)[tid] = ((const float4*)(user_emb + (size_t)uid * EE))[tid];
    }
    if (tid >= 64 && tid < 64 + EE) {
        s_bias2[tid - 64] = feat_b2[tid - 64];
        s_w2[tid - 64]    = w2[tid - 64];
    }
    __syncthreads();

    // ---- fp32 user folds: bias1 = W1a@user + feat_b1 ; bias3 = W3a@user + b1 ----
    if (tid < 256) {
        const int e    = tid & (EE - 1);
        const int half = tid >> 7;
        const float* wrow = half ? (w1 + (size_t)e * (3 * EE))
                                 : (feat_w1 + (size_t)e * (EE + FF));
        float acc = 0.f;
        #pragma unroll 8
        for (int k = 0; k < EE; ++k) acc += wrow[k] * s_user[k];
        if (half == 0) s_bias1[e] = acc + feat_b1[e];
        else           s_bias3[e] = acc + b1[e];
    }
    __syncthreads();

    const float bias1_0 = s_bias1[n0];
    const float bias2_0 = s_bias2[n0];
    const float bias3_0 = s_bias3[n0];
    const float w2_0    = s_w2[n0];

    // ---- chunk loop: 13 M-tiles of 16 rows, in 7 chunks of (2,...,2,1) tiles ----
    for (int ch = 0; ch < NCH; ++ch) {
        const int row0 = ch * CROWS;
        const int ntl  = (ch < NCH - 1) ? 2 : 1;
        const int rows = ntl * 16;

        // fold PREVIOUS chunk's per-wave logit partials -> s_logit
        // (s_lp was complete before the last barrier; overwritten only at this
        //  chunk's L3, three barriers from now)
        if (ch > 0 && tid < CROWS) {
            float p = 0.f;
            #pragma unroll
            for (int w = 0; w < 8; ++w) p += s_lp[w][tid];
            s_logit[row0 - CROWS + tid] = p;
        }

        // stage features -> bf16 LDS [row][k] (pad rows = 0)
        for (int idx = tid; idx < rows * 16; idx += NTHREADS) {
            const int r = idx >> 4, c4 = idx & 15;
            const int l = row0 + r;
            float4 v = make_float4(0.f, 0.f, 0.f, 0.f);
            if (l < LL) v = ((const float4*)features)[((size_t)b * LL + l) * 16 + c4];
            *(uint2*)&s_feat[r * PITCH_F + c4 * 4] = pk4(v);
        }
        // stage gathered item rows -> bf16 LDS x3[row][0..127]
        for (int idx = tid; idx < rows * 32; idx += NTHREADS) {
            const int r = idx >> 5, c4 = idx & 31;
            const int l = row0 + r;
            float4 v = make_float4(0.f, 0.f, 0.f, 0.f);
            if (l < LL) {
                const int id = item_ids[(size_t)b * LL + l];
                v = ((const float4*)item_emb)[(size_t)id * 32 + c4];
            }
            *(uint2*)&s_x3[r * PITCH_X3 + c4 * 4] = pk4(v);
        }
        __syncthreads();

        // layer 1: fx = relu(feat @ W1f^T + bias1)
        for (int mt = 0; mt < ntl; ++mt) {
            floatx4 a0 = {0.f, 0.f, 0.f, 0.f};
            const unsigned short* ap = s_feat + (mt * 16 + m) * PITCH_F + q * 8;
            #pragma unroll
            for (int ks = 0; ks < 2; ++ks) {
                shortx8 af = *(const shortx8*)(ap + ks * 32);
                a0 = MFMA16(af, B1[ks], a0);
            }
            #pragma unroll
            for (int r = 0; r < 4; ++r) {
                const int row = mt * 16 + q * 4 + r;
                float v0 = a0[r] + bias1_0; v0 = v0 > 0.f ? v0 : 0.f;
                s_fx[row * PITCH_FX + n0] = f2bf(v0);
            }
        }
        __syncthreads();

        // layer 2: comp = relu(fx @ W2^T + bias2) -> x3 cols 128..255
        for (int mt = 0; mt < ntl; ++mt) {
            floatx4 a0 = {0.f, 0.f, 0.f, 0.f};
            const unsigned short* ap = s_fx + (mt * 16 + m) * PITCH_FX + q * 8;
            #pragma unroll
            for (int ks = 0; ks < 4; ++ks) {
                shortx8 af = *(const shortx8*)(ap + ks * 32);
                a0 = MFMA16(af, B2[ks], a0);
            }
            #pragma unroll
            for (int r = 0; r < 4; ++r) {
                const int row = mt * 16 + q * 4 + r;
                float v0 = a0[r] + bias2_0; v0 = v0 > 0.f ? v0 : 0.f;
                s_x3[row * PITCH_X3 + EE + n0] = f2bf(v0);
            }
        }
        __syncthreads();

        // layer 3: h = relu([items|comp] @ W3'^T + bias3); logit partial = w2[n]*h
        for (int mt = 0; mt < ntl; ++mt) {
            floatx4 a0 = {0.f, 0.f, 0.f, 0.f};
            const unsigned short* ap = s_x3 + (mt * 16 + m) * PITCH_X3 + q * 8;
            #pragma unroll
            for (int ks = 0; ks < 8; ++ks) {
                shortx8 af = *(const shortx8*)(ap + ks * 32);
                a0 = MFMA16(af, B3[ks], a0);
            }
            #pragma unroll
            for (int r = 0; r < 4; ++r) {
                float v0 = a0[r] + bias3_0; v0 = v0 > 0.f ? v0 : 0.f;
                float p = v0 * w2_0;
                p += __shfl_xor(p, 1, 64);   // reduce over the 16-lane n dim
                p += __shfl_xor(p, 2, 64);
                p += __shfl_xor(p, 4, 64);
                p += __shfl_xor(p, 8, 64);
                if (m == 0) s_lp[wv][mt * 16 + q * 4 + r] = p;
            }
        }
        __syncthreads();
    }

    // fold the last chunk's partials (1 tile = 16 rows; rows >= 200 are garbage,
    // masked below)
    if (tid < 16) {
        float p = 0.f;
        #pragma unroll
        for (int w = 0; w < 8; ++w) p += s_lp[w][tid];
        s_logit[(NCH - 1) * CROWS + tid] = p;
    }
    __syncthreads();

    // ---- softmax over L=200 (b2 is a constant shift -> cancels in softmax) ----
    const int wid = tid >> 6;
    float lv = (tid < LL) ? s_logit[tid] : -INFINITY;
    {
        float mx = waveMax(lv);
        if ((tid & 63) == 0) s_red[wid] = mx;
        __syncthreads();
        if (tid == 0) {
            float g = s_red[0];
            #pragma unroll
            for (int w = 1; w < 8; ++w) g = fmaxf(g, s_red[w]);
            s_red[8] = g;
        }
        __syncthreads();
    }
    const float gmax = s_red[8];
    __syncthreads();
    float ex = (tid < LL) ? __expf(lv - gmax) : 0.f;
    {
        float s = waveSum(ex);
        if ((tid & 63) == 0) s_red[wid] = s;
        __syncthreads();
        if (tid == 0) {
            float g = 0.f;
            #pragma unroll
            for (int w = 0; w < 8; ++w) g += s_red[w];
            s_red[8] = g;
        }
        __syncthreads();
    }
    const float inv = 1.f / s_red[8];
    if (tid < LL) s_attn[tid] = ex * inv;
    __syncthreads();

    // ---- out[b] = user + sum_l attn[l] * item_emb[item_ids[b,l]]  (fp32) ----
    {
        const int e = tid & (EE - 1);
        const int g = tid >> 7;            // 0..3, each covers 50 l's
        float acc = 0.f;
        const int lstart = g * (LL / 4);
        for (int l = lstart; l < lstart + LL / 4; ++l) {
            const float a  = s_attn[l];
            const int  id  = item_ids[(size_t)b * LL + l];
            acc += a * item_emb[(size_t)id * EE + e];
        }
        s_part[g][e] = acc;
        __syncthreads();
        if (tid < EE)
            out[(size_t)b * EE + tid] = s_user[tid] + s_part[0][tid] + s_part[1][tid]
                                      + s_part[2][tid] + s_part[3][tid];
    }
}

extern "C" void kernel_launch(void* const* d_in, const int* in_sizes, int n_in,
                              void* d_out, int out_size, void* d_ws, size_t ws_size,
                              hipStream_t stream) {
    const int*   user_ids = (const int*)  d_in[0];
    const int*   item_ids = (const int*)  d_in[1];
    const float* features = (const float*)d_in[2];
    const float* user_emb = (const float*)d_in[3];
    const float* item_emb = (const float*)d_in[4];
    const float* feat_w1  = (const float*)d_in[5];
    const float* feat_b1  = (const float*)d_in[6];
    const float* feat_w2  = (const float*)d_in[7];
    const float* feat_b2  = (const float*)d_in[8];
    const float* w1       = (const float*)d_in[9];
    const float* b1       = (const float*)d_in[10];
    const float* w2       = (const float*)d_in[11];
    const float* b2       = (const float*)d_in[12];
    float* out = (float*)d_out;

    usernet_mfma<<<BB, NTHREADS, 0, stream>>>(user_ids, item_ids, features,
                                              user_emb, item_emb,
                                              feat_w1, feat_b1, feat_w2, feat_b2,
                                              w1, b1, w2, b2, out);
}

// Round 4
// 747.567 us; speedup vs baseline: 1.2478x; 1.2478x over previous
//
#include <hip/hip_runtime.h>
#include <math.h>

#define BB 4096
#define LL 200
#define EE 128
#define FF 64
#define NTHREADS 512   // 8 waves; each wave owns 16 output columns (one N-tile)

#define CROWS 32       // M-rows staged per chunk (2 MFMA M-tiles).
                       // 32-row chunks cut LDS to ~37.9 KB -> 4 blocks/CU by LDS.
#define NCH 7          // ceil(200/32) chunks: 6 full (2 tiles) + 1 tail (1 tile)

// LDS row pitches (bf16 elems). pitch_bytes = 16*odd -> A-operand ds_read_b128
// 16B-column index = (9m+q) mod 8, uniform -> conflict-free.
#define PITCH_F  72     // features K=64  (+8 pad), 144 B = 16*9
#define PITCH_FX 136    // fx       K=128 (+8 pad), 272 B = 16*17
#define PITCH_X3 264    // items|comp K=256 (+8 pad), 528 B = 16*33

typedef __attribute__((ext_vector_type(4))) float  floatx4;
typedef __attribute__((ext_vector_type(8))) short  shortx8;

#define MFMA16(a, b, c) __builtin_amdgcn_mfma_f32_16x16x32_bf16((a), (b), (c), 0, 0, 0)

// HW packed f32->bf16 RTNE: 1 VALU op per 2 elements.
__device__ __forceinline__ unsigned cvt_pk_bf16(float lo, float hi) {
    unsigned r;
    asm("v_cvt_pk_bf16_f32 %0, %1, %2" : "=v"(r) : "v"(lo), "v"(hi));
    return r;
}
__device__ __forceinline__ unsigned short f2bf(float f) {
    return (unsigned short)cvt_pk_bf16(f, f);   // src0 lands in low 16 bits
}
__device__ __forceinline__ uint2 pk4(float4 v) {
    uint2 o;
    o.x = cvt_pk_bf16(v.x, v.y);
    o.y = cvt_pk_bf16(v.z, v.w);
    return o;
}

// load 8 consecutive fp32, round to bf16, return MFMA B-fragment
__device__ __forceinline__ shortx8 load_bfrag(const float* p) {
    float4 v0 = ((const float4*)p)[0];
    float4 v1 = ((const float4*)p)[1];
    union { unsigned u[4]; shortx8 s; } r;
    r.u[0] = cvt_pk_bf16(v0.x, v0.y);
    r.u[1] = cvt_pk_bf16(v0.z, v0.w);
    r.u[2] = cvt_pk_bf16(v1.x, v1.y);
    r.u[3] = cvt_pk_bf16(v1.z, v1.w);
    return r.s;
}

__device__ __forceinline__ float waveMax(float v) {
    #pragma unroll
    for (int off = 32; off > 0; off >>= 1)
        v = fmaxf(v, __shfl_xor(v, off, 64));
    return v;
}
__device__ __forceinline__ float waveSum(float v) {
    #pragma unroll
    for (int off = 32; off > 0; off >>= 1)
        v += __shfl_xor(v, off, 64);
    return v;
}

// bound (512,4): 128-reg budget. The kernel needs ~64-75 live regs (B-frags=56);
// bound (512,8) forced a 64-reg budget -> 32 arch VGPRs -> scratch spill
// (FETCH 528->1513 MB, WRITE 117->609 MB, dur +27%). Actual occupancy follows
// the ACTUAL VGPR count (64 -> 8 waves/SIMD), so declare the loose bound and
// let LDS (37.9 KB -> 4 blocks/CU) set residency.
__global__ __launch_bounds__(NTHREADS, 4)
void usernet_mfma(const int* __restrict__ user_ids,
                  const int* __restrict__ item_ids,
                  const float* __restrict__ features,
                  const float* __restrict__ user_emb,
                  const float* __restrict__ item_emb,
                  const float* __restrict__ feat_w1,
                  const float* __restrict__ feat_b1,
                  const float* __restrict__ feat_w2,
                  const float* __restrict__ feat_b2,
                  const float* __restrict__ w1,
                  const float* __restrict__ b1,
                  const float* __restrict__ w2,
                  const float* __restrict__ b2,
                  float* __restrict__ out)
{
    // big-3 staging buffers: 4608 + 8704 + 16896 = 30208 B
    __shared__ __align__(16) unsigned short s_feat[CROWS * PITCH_F];
    __shared__ __align__(16) unsigned short s_fx  [CROWS * PITCH_FX];
    __shared__ __align__(16) unsigned short s_x3  [CROWS * PITCH_X3];
    __shared__ float s_user[EE];
    __shared__ float s_bias1[EE];     // u1 + feat_b1
    __shared__ float s_bias2[EE];     // feat_b2
    __shared__ float s_bias3[EE];     // u3 + b1
    __shared__ float s_w2[EE];
    __shared__ float s_lp[8][CROWS];  // per-wave logit partials, current chunk only (1 KB)
    __shared__ float s_logit[208];    // folded logits, all rows
    __shared__ float s_attn[208];
    __shared__ float s_red[12];
    __shared__ float s_part[4][EE];
    // total ~37.9 KB -> 4 blocks/CU

    const int b    = blockIdx.x;
    const int tid  = threadIdx.x;
    const int lane = tid & 63;
    const int wv   = tid >> 6;         // wave id 0..7: owns output cols [16*wv, 16*wv+16)
    const int m    = lane & 15;
    const int q    = lane >> 4;
    const int n0   = wv * 16 + m;      // owned output col for this lane

    // ---- persistent B fragments (56 VGPRs/wave; user cols folded out) ----
    shortx8 B1[2];   // feat_w1 features part, K=64
    shortx8 B2[4];   // feat_w2, K=128
    shortx8 B3[8];   // w1 item|comp part, K=256
    #pragma unroll
    for (int ks = 0; ks < 2; ++ks)
        B1[ks] = load_bfrag(feat_w1 + (size_t)n0 * (EE + FF) + EE + ks * 32 + q * 8);
    #pragma unroll
    for (int ks = 0; ks < 4; ++ks)
        B2[ks] = load_bfrag(feat_w2 + (size_t)n0 * EE + ks * 32 + q * 8);
    #pragma unroll
    for (int ks = 0; ks < 8; ++ks)
        B3[ks] = load_bfrag(w1 + (size_t)n0 * (3 * EE) + EE + ks * 32 + q * 8);

    // ---- user row + small vectors ----
    if (tid < 32) {
        const int uid = user_ids[b];
        ((float4*)s_user)[tid] = ((const float4*)(user_emb + (size_t)uid * EE))[tid];
    }
    if (tid >= 64 && tid < 64 + EE) {
        s_bias2[tid - 64] = feat_b2[tid - 64];
        s_w2[tid - 64]    = w2[tid - 64];
    }
    __syncthreads();

    // ---- fp32 user folds: bias1 = W1a@user + feat_b1 ; bias3 = W3a@user + b1 ----
    if (tid < 256) {
        const int e    = tid & (EE - 1);
        const int half = tid >> 7;
        const float* wrow = half ? (w1 + (size_t)e * (3 * EE))
                                 : (feat_w1 + (size_t)e * (EE + FF));
        float acc = 0.f;
        #pragma unroll 8
        for (int k = 0; k < EE; ++k) acc += wrow[k] * s_user[k];
        if (half == 0) s_bias1[e] = acc + feat_b1[e];
        else           s_bias3[e] = acc + b1[e];
    }
    __syncthreads();

    const float bias1_0 = s_bias1[n0];
    const float bias2_0 = s_bias2[n0];
    const float bias3_0 = s_bias3[n0];
    const float w2_0    = s_w2[n0];

    // ---- chunk loop: 13 M-tiles of 16 rows, in 7 chunks of (2,...,2,1) tiles ----
    for (int ch = 0; ch < NCH; ++ch) {
        const int row0 = ch * CROWS;
        const int ntl  = (ch < NCH - 1) ? 2 : 1;
        const int rows = ntl * 16;

        // fold PREVIOUS chunk's per-wave logit partials -> s_logit
        // (s_lp was complete before the last barrier; overwritten only at this
        //  chunk's L3, three barriers from now)
        if (ch > 0 && tid < CROWS) {
            float p = 0.f;
            #pragma unroll
            for (int w = 0; w < 8; ++w) p += s_lp[w][tid];
            s_logit[row0 - CROWS + tid] = p;
        }

        // stage features -> bf16 LDS [row][k] (pad rows = 0)
        for (int idx = tid; idx < rows * 16; idx += NTHREADS) {
            const int r = idx >> 4, c4 = idx & 15;
            const int l = row0 + r;
            float4 v = make_float4(0.f, 0.f, 0.f, 0.f);
            if (l < LL) v = ((const float4*)features)[((size_t)b * LL + l) * 16 + c4];
            *(uint2*)&s_feat[r * PITCH_F + c4 * 4] = pk4(v);
        }
        // stage gathered item rows -> bf16 LDS x3[row][0..127]
        for (int idx = tid; idx < rows * 32; idx += NTHREADS) {
            const int r = idx >> 5, c4 = idx & 31;
            const int l = row0 + r;
            float4 v = make_float4(0.f, 0.f, 0.f, 0.f);
            if (l < LL) {
                const int id = item_ids[(size_t)b * LL + l];
                v = ((const float4*)item_emb)[(size_t)id * 32 + c4];
            }
            *(uint2*)&s_x3[r * PITCH_X3 + c4 * 4] = pk4(v);
        }
        __syncthreads();

        // layer 1: fx = relu(feat @ W1f^T + bias1)
        for (int mt = 0; mt < ntl; ++mt) {
            floatx4 a0 = {0.f, 0.f, 0.f, 0.f};
            const unsigned short* ap = s_feat + (mt * 16 + m) * PITCH_F + q * 8;
            #pragma unroll
            for (int ks = 0; ks < 2; ++ks) {
                shortx8 af = *(const shortx8*)(ap + ks * 32);
                a0 = MFMA16(af, B1[ks], a0);
            }
            #pragma unroll
            for (int r = 0; r < 4; ++r) {
                const int row = mt * 16 + q * 4 + r;
                float v0 = a0[r] + bias1_0; v0 = v0 > 0.f ? v0 : 0.f;
                s_fx[row * PITCH_FX + n0] = f2bf(v0);
            }
        }
        __syncthreads();

        // layer 2: comp = relu(fx @ W2^T + bias2) -> x3 cols 128..255
        for (int mt = 0; mt < ntl; ++mt) {
            floatx4 a0 = {0.f, 0.f, 0.f, 0.f};
            const unsigned short* ap = s_fx + (mt * 16 + m) * PITCH_FX + q * 8;
            #pragma unroll
            for (int ks = 0; ks < 4; ++ks) {
                shortx8 af = *(const shortx8*)(ap + ks * 32);
                a0 = MFMA16(af, B2[ks], a0);
            }
            #pragma unroll
            for (int r = 0; r < 4; ++r) {
                const int row = mt * 16 + q * 4 + r;
                float v0 = a0[r] + bias2_0; v0 = v0 > 0.f ? v0 : 0.f;
                s_x3[row * PITCH_X3 + EE + n0] = f2bf(v0);
            }
        }
        __syncthreads();

        // layer 3: h = relu([items|comp] @ W3'^T + bias3); logit partial = w2[n]*h
        for (int mt = 0; mt < ntl; ++mt) {
            floatx4 a0 = {0.f, 0.f, 0.f, 0.f};
            const unsigned short* ap = s_x3 + (mt * 16 + m) * PITCH_X3 + q * 8;
            #pragma unroll
            for (int ks = 0; ks < 8; ++ks) {
                shortx8 af = *(const shortx8*)(ap + ks * 32);
                a0 = MFMA16(af, B3[ks], a0);
            }
            #pragma unroll
            for (int r = 0; r < 4; ++r) {
                float v0 = a0[r] + bias3_0; v0 = v0 > 0.f ? v0 : 0.f;
                float p = v0 * w2_0;
                p += __shfl_xor(p, 1, 64);   // reduce over the 16-lane n dim
                p += __shfl_xor(p, 2, 64);
                p += __shfl_xor(p, 4, 64);
                p += __shfl_xor(p, 8, 64);
                if (m == 0) s_lp[wv][mt * 16 + q * 4 + r] = p;
            }
        }
        __syncthreads();
    }

    // fold the last chunk's partials (1 tile = 16 rows; rows >= 200 are garbage,
    // masked below)
    if (tid < 16) {
        float p = 0.f;
        #pragma unroll
        for (int w = 0; w < 8; ++w) p += s_lp[w][tid];
        s_logit[(NCH - 1) * CROWS + tid] = p;
    }
    __syncthreads();

    // ---- softmax over L=200 (b2 is a constant shift -> cancels in softmax) ----
    const int wid = tid >> 6;
    float lv = (tid < LL) ? s_logit[tid] : -INFINITY;
    {
        float mx = waveMax(lv);
        if ((tid & 63) == 0) s_red[wid] = mx;
        __syncthreads();
        if (tid == 0) {
            float g = s_red[0];
            #pragma unroll
            for (int w = 1; w < 8; ++w) g = fmaxf(g, s_red[w]);
            s_red[8] = g;
        }
        __syncthreads();
    }
    const float gmax = s_red[8];
    __syncthreads();
    float ex = (tid < LL) ? __expf(lv - gmax) : 0.f;
    {
        float s = waveSum(ex);
        if ((tid & 63) == 0) s_red[wid] = s;
        __syncthreads();
        if (tid == 0) {
            float g = 0.f;
            #pragma unroll
            for (int w = 0; w < 8; ++w) g += s_red[w];
            s_red[8] = g;
        }
        __syncthreads();
    }
    const float inv = 1.f / s_red[8];
    if (tid < LL) s_attn[tid] = ex * inv;
    __syncthreads();

    // ---- out[b] = user + sum_l attn[l] * item_emb[item_ids[b,l]]  (fp32) ----
    {
        const int e = tid & (EE - 1);
        const int g = tid >> 7;            // 0..3, each covers 50 l's
        float acc = 0.f;
        const int lstart = g * (LL / 4);
        for (int l = lstart; l < lstart + LL / 4; ++l) {
            const float a  = s_attn[l];
            const int  id  = item_ids[(size_t)b * LL + l];
            acc += a * item_emb[(size_t)id * EE + e];
        }
        s_part[g][e] = acc;
        __syncthreads();
        if (tid < EE)
            out[(size_t)b * EE + tid] = s_user[tid] + s_part[0][tid] + s_part[1][tid]
                                      + s_part[2][tid] + s_part[3][tid];
    }
}

extern "C" void kernel_launch(void* const* d_in, const int* in_sizes, int n_in,
                              void* d_out, int out_size, void* d_ws, size_t ws_size,
                              hipStream_t stream) {
    const int*   user_ids = (const int*)  d_in[0];
    const int*   item_ids = (const int*)  d_in[1];
    const float* features = (const float*)d_in[2];
    const float* user_emb = (const float*)d_in[3];
    const float* item_emb = (const float*)d_in[4];
    const float* feat_w1  = (const float*)d_in[5];
    const float* feat_b1  = (const float*)d_in[6];
    const float* feat_w2  = (const float*)d_in[7];
    const float* feat_b2  = (const float*)d_in[8];
    const float* w1       = (const float*)d_in[9];
    const float* b1       = (const float*)d_in[10];
    const float* w2       = (const float*)d_in[11];
    const float* b2       = (const float*)d_in[12];
    float* out = (float*)d_out;

    usernet_mfma<<<BB, NTHREADS, 0, stream>>>(user_ids, item_ids, features,
                                              user_emb, item_emb,
                                              feat_w1, feat_b1, feat_w2, feat_b2,
                                              w1, b1, w2, b2, out);
}

// Round 5
// 701.041 us; speedup vs baseline: 1.3306x; 1.0664x over previous
//
#include <hip/hip_runtime.h>
#include <math.h>

#define BB 4096
#define LL 200
#define EE 128
#define FF 64
#define NTHREADS 512   // 8 waves; each wave owns 16 output columns (one N-tile)

#define CROWS 32       // M-rows staged per chunk (2 MFMA M-tiles)
#define NCH 7          // ceil(200/32) chunks: 6 full (2 tiles) + 1 tail (1 tile)

// LDS row pitches (bf16 elems). pitch_bytes = 16*odd -> A-operand ds_read_b128
// 16B-column index = (9m+q) mod 8, uniform -> conflict-free.
#define PITCH_F  72     // features K=64  (+8 pad), 144 B = 16*9
#define PITCH_FX 136    // fx / items / comp, K=128 (+8 pad), 272 B = 16*17

typedef __attribute__((ext_vector_type(4))) float  floatx4;
typedef __attribute__((ext_vector_type(8))) short  shortx8;

#define MFMA16(a, b, c) __builtin_amdgcn_mfma_f32_16x16x32_bf16((a), (b), (c), 0, 0, 0)

// HW packed f32->bf16 RTNE: 1 VALU op per 2 elements.
__device__ __forceinline__ unsigned cvt_pk_bf16(float lo, float hi) {
    unsigned r;
    asm("v_cvt_pk_bf16_f32 %0, %1, %2" : "=v"(r) : "v"(lo), "v"(hi));
    return r;
}
__device__ __forceinline__ unsigned short f2bf(float f) {
    return (unsigned short)cvt_pk_bf16(f, f);   // src0 lands in low 16 bits
}
__device__ __forceinline__ uint2 pk4(float4 v) {
    uint2 o;
    o.x = cvt_pk_bf16(v.x, v.y);
    o.y = cvt_pk_bf16(v.z, v.w);
    return o;
}

// load 8 consecutive fp32, round to bf16, return MFMA B-fragment
__device__ __forceinline__ shortx8 load_bfrag(const float* p) {
    float4 v0 = ((const float4*)p)[0];
    float4 v1 = ((const float4*)p)[1];
    union { unsigned u[4]; shortx8 s; } r;
    r.u[0] = cvt_pk_bf16(v0.x, v0.y);
    r.u[1] = cvt_pk_bf16(v0.z, v0.w);
    r.u[2] = cvt_pk_bf16(v1.x, v1.y);
    r.u[3] = cvt_pk_bf16(v1.z, v1.w);
    return r.s;
}

__device__ __forceinline__ float waveMax(float v) {
    #pragma unroll
    for (int off = 32; off > 0; off >>= 1)
        v = fmaxf(v, __shfl_xor(v, off, 64));
    return v;
}
__device__ __forceinline__ float waveSum(float v) {
    #pragma unroll
    for (int off = 32; off > 0; off >>= 1)
        v += __shfl_xor(v, off, 64);
    return v;
}

// Prefetch chunk data (features + gathered item rows) into registers.
// Per thread: 1 float4 of features (32x16 float4 = 512 = NTHREADS) and
// 2 float4 of item rows (32x32 float4 = 1024 = 2*NTHREADS). 12 VGPRs live.
__device__ __forceinline__ void pf_load(int b, int row0n, int tid, bool en,
                                        const float* __restrict__ features,
                                        const int* __restrict__ item_ids,
                                        const float* __restrict__ item_emb,
                                        float4& f, float4& i0, float4& i1)
{
    f  = make_float4(0.f, 0.f, 0.f, 0.f);
    i0 = make_float4(0.f, 0.f, 0.f, 0.f);
    i1 = make_float4(0.f, 0.f, 0.f, 0.f);
    if (!en) return;
    {
        const int r = tid >> 4, c4 = tid & 15, l = row0n + r;
        if (l < LL) f = ((const float4*)features)[((size_t)b * LL + l) * 16 + c4];
    }
    {
        const int r = tid >> 5, c4 = tid & 31, l = row0n + r;
        if (l < LL) {
            const int id = item_ids[(size_t)b * LL + l];
            i0 = ((const float4*)item_emb)[(size_t)id * 32 + c4];
        }
    }
    {
        const int idx = tid + NTHREADS;
        const int r = idx >> 5, c4 = idx & 31, l = row0n + r;
        if (l < LL) {
            const int id = item_ids[(size_t)b * LL + l];
            i1 = ((const float4*)item_emb)[(size_t)id * 32 + c4];
        }
    }
}

__device__ __forceinline__ void pf_store(int tid, unsigned short* s_feat,
                                         unsigned short* s_it_dst,
                                         const float4& f, const float4& i0,
                                         const float4& i1)
{
    {
        const int r = tid >> 4, c4 = tid & 15;
        *(uint2*)&s_feat[r * PITCH_F + c4 * 4] = pk4(f);
    }
    {
        const int r = tid >> 5, c4 = tid & 31;
        *(uint2*)&s_it_dst[r * PITCH_FX + c4 * 4] = pk4(i0);
    }
    {
        const int idx = tid + NTHREADS;
        const int r = idx >> 5, c4 = idx & 31;
        *(uint2*)&s_it_dst[r * PITCH_FX + c4 * 4] = pk4(i1);
    }
}

// bound (512,4): 128-reg total budget. (512,8)'s 64-reg budget spilled
// catastrophically (R3: FETCH +1GB, WRITE +0.5GB). Measured residency is
// REGISTER-limited to 2 blocks/CU (R3 vs R4 cross-check), so LDS up to
// ~75 KB/block is free — spent here on ping-pong item staging.
__global__ __launch_bounds__(NTHREADS, 4)
void usernet_mfma(const int* __restrict__ user_ids,
                  const int* __restrict__ item_ids,
                  const float* __restrict__ features,
                  const float* __restrict__ user_emb,
                  const float* __restrict__ item_emb,
                  const float* __restrict__ feat_w1,
                  const float* __restrict__ feat_b1,
                  const float* __restrict__ feat_w2,
                  const float* __restrict__ feat_b2,
                  const float* __restrict__ w1,
                  const float* __restrict__ b1,
                  const float* __restrict__ w2,
                  const float* __restrict__ b2,
                  float* __restrict__ out)
{
    // staging buffers: feat 4608 + it 2x8704 + fx 8704 + comp 8704 = 39.4 KB
    __shared__ __align__(16) unsigned short s_feat[CROWS * PITCH_F];
    __shared__ __align__(16) unsigned short s_it  [2][CROWS * PITCH_FX];  // ping-pong items
    __shared__ __align__(16) unsigned short s_fx  [CROWS * PITCH_FX];
    __shared__ __align__(16) unsigned short s_comp[CROWS * PITCH_FX];
    __shared__ float s_user[EE];
    __shared__ float s_bias1[EE];     // u1 + feat_b1
    __shared__ float s_bias2[EE];     // feat_b2
    __shared__ float s_bias3[EE];     // u3 + b1
    __shared__ float s_w2[EE];
    __shared__ float s_lp[8][CROWS];  // per-wave logit partials, current chunk only
    __shared__ float s_logit[224];    // folded logits, all rows
    __shared__ float s_attn[208];
    __shared__ float s_red[12];
    __shared__ float s_part[4][EE];
    // total ~46.8 KB -> still 2 blocks/CU (register-limited anyway)

    const int b    = blockIdx.x;
    const int tid  = threadIdx.x;
    const int lane = tid & 63;
    const int wv   = tid >> 6;         // wave id 0..7: owns output cols [16*wv, 16*wv+16)
    const int m    = lane & 15;
    const int q    = lane >> 4;
    const int n0   = wv * 16 + m;      // owned output col for this lane

    // ---- persistent B fragments (56 VGPRs/wave; user cols folded out) ----
    shortx8 B1[2];   // feat_w1 features part, K=64
    shortx8 B2[4];   // feat_w2, K=128
    shortx8 B3[8];   // w1 item|comp part, K=256 (0..3 items, 4..7 comp)
    #pragma unroll
    for (int ks = 0; ks < 2; ++ks)
        B1[ks] = load_bfrag(feat_w1 + (size_t)n0 * (EE + FF) + EE + ks * 32 + q * 8);
    #pragma unroll
    for (int ks = 0; ks < 4; ++ks)
        B2[ks] = load_bfrag(feat_w2 + (size_t)n0 * EE + ks * 32 + q * 8);
    #pragma unroll
    for (int ks = 0; ks < 8; ++ks)
        B3[ks] = load_bfrag(w1 + (size_t)n0 * (3 * EE) + EE + ks * 32 + q * 8);

    // ---- user row + small vectors ----
    if (tid < 32) {
        const int uid = user_ids[b];
        ((float4*)s_user)[tid] = ((const float4*)(user_emb + (size_t)uid * EE))[tid];
    }
    if (tid >= 64 && tid < 64 + EE) {
        s_bias2[tid - 64] = feat_b2[tid - 64];
        s_w2[tid - 64]    = w2[tid - 64];
    }
    __syncthreads();

    // ---- fp32 user folds: bias1 = W1a@user + feat_b1 ; bias3 = W3a@user + b1 ----
    if (tid < 256) {
        const int e    = tid & (EE - 1);
        const int half = tid >> 7;
        const float* wrow = half ? (w1 + (size_t)e * (3 * EE))
                                 : (feat_w1 + (size_t)e * (EE + FF));
        float acc = 0.f;
        #pragma unroll 8
        for (int k = 0; k < EE; ++k) acc += wrow[k] * s_user[k];
        if (half == 0) s_bias1[e] = acc + feat_b1[e];
        else           s_bias3[e] = acc + b1[e];
    }

    // ---- prologue: stage chunk 0 (overlaps the bias fold above) ----
    float4 pf_f, pf_i0, pf_i1;
    pf_load(b, 0, tid, true, features, item_ids, item_emb, pf_f, pf_i0, pf_i1);
    pf_store(tid, s_feat, s_it[0], pf_f, pf_i0, pf_i1);
    __syncthreads();

    const float bias1_0 = s_bias1[n0];
    const float bias2_0 = s_bias2[n0];
    const float bias3_0 = s_bias3[n0];
    const float w2_0    = s_w2[n0];

    // ---- chunk loop: per chunk {issue ch+1 loads | L1 | L2 | L3 + stage ch+1} ----
    for (int ch = 0; ch < NCH; ++ch) {
        const int row0 = ch * CROWS;
        const int ntl  = (ch < NCH - 1) ? 2 : 1;
        const unsigned short* s_itc = s_it[ch & 1];

        // issue global loads for chunk ch+1 NOW; consumed after L3 (latency
        // hides under L1+L2+L3 compute ~3 barrier-phases). T14 async-stage.
        pf_load(b, (ch + 1) * CROWS, tid, ch + 1 < NCH,
                features, item_ids, item_emb, pf_f, pf_i0, pf_i1);

        // fold PREVIOUS chunk's per-wave logit partials -> s_logit
        // (s_lp complete as of last barrier; rewritten only in this chunk's L3,
        //  two barriers from here)
        if (ch > 0 && tid < CROWS) {
            float p = 0.f;
            #pragma unroll
            for (int w = 0; w < 8; ++w) p += s_lp[w][tid];
            s_logit[row0 - CROWS + tid] = p;
        }

        // layer 1: fx = relu(feat @ W1f^T + bias1)
        for (int mt = 0; mt < ntl; ++mt) {
            floatx4 a0 = {0.f, 0.f, 0.f, 0.f};
            const unsigned short* ap = s_feat + (mt * 16 + m) * PITCH_F + q * 8;
            #pragma unroll
            for (int ks = 0; ks < 2; ++ks) {
                shortx8 af = *(const shortx8*)(ap + ks * 32);
                a0 = MFMA16(af, B1[ks], a0);
            }
            #pragma unroll
            for (int r = 0; r < 4; ++r) {
                const int row = mt * 16 + q * 4 + r;
                float v0 = a0[r] + bias1_0; v0 = v0 > 0.f ? v0 : 0.f;
                s_fx[row * PITCH_FX + n0] = f2bf(v0);
            }
        }
        __syncthreads();

        // layer 2: comp = relu(fx @ W2^T + bias2)
        for (int mt = 0; mt < ntl; ++mt) {
            floatx4 a0 = {0.f, 0.f, 0.f, 0.f};
            const unsigned short* ap = s_fx + (mt * 16 + m) * PITCH_FX + q * 8;
            #pragma unroll
            for (int ks = 0; ks < 4; ++ks) {
                shortx8 af = *(const shortx8*)(ap + ks * 32);
                a0 = MFMA16(af, B2[ks], a0);
            }
            #pragma unroll
            for (int r = 0; r < 4; ++r) {
                const int row = mt * 16 + q * 4 + r;
                float v0 = a0[r] + bias2_0; v0 = v0 > 0.f ? v0 : 0.f;
                s_comp[row * PITCH_FX + n0] = f2bf(v0);
            }
        }
        __syncthreads();

        // layer 3: h = relu([items|comp] @ W3'^T + bias3); logit partial = w2[n]*h
        for (int mt = 0; mt < ntl; ++mt) {
            floatx4 a0 = {0.f, 0.f, 0.f, 0.f};
            const unsigned short* api = s_itc  + (mt * 16 + m) * PITCH_FX + q * 8;
            const unsigned short* apc = s_comp + (mt * 16 + m) * PITCH_FX + q * 8;
            #pragma unroll
            for (int ks = 0; ks < 4; ++ks) {
                shortx8 af = *(const shortx8*)(api + ks * 32);
                a0 = MFMA16(af, B3[ks], a0);
            }
            #pragma unroll
            for (int ks = 0; ks < 4; ++ks) {
                shortx8 af = *(const shortx8*)(apc + ks * 32);
                a0 = MFMA16(af, B3[4 + ks], a0);
            }
            #pragma unroll
            for (int r = 0; r < 4; ++r) {
                float v0 = a0[r] + bias3_0; v0 = v0 > 0.f ? v0 : 0.f;
                float p = v0 * w2_0;
                p += __shfl_xor(p, 1, 64);   // reduce over the 16-lane n dim
                p += __shfl_xor(p, 2, 64);
                p += __shfl_xor(p, 4, 64);
                p += __shfl_xor(p, 8, 64);
                if (m == 0) s_lp[wv][mt * 16 + q * 4 + r] = p;
            }
        }

        // stage chunk ch+1 from the prefetch regs (s_feat safe: its L1 reads
        // finished two barriers ago; items go to the other ping-pong buffer)
        if (ch + 1 < NCH)
            pf_store(tid, s_feat, s_it[(ch + 1) & 1], pf_f, pf_i0, pf_i1);
        __syncthreads();   // s_lp ready + ch+1 staged + s_fx/s_comp reusable
    }

    // fold the last chunk's partials (1 tile = 16 rows)
    if (tid < 16) {
        float p = 0.f;
        #pragma unroll
        for (int w = 0; w < 8; ++w) p += s_lp[w][tid];
        s_logit[(NCH - 1) * CROWS + tid] = p;
    }
    __syncthreads();

    // ---- softmax over L=200 (b2 is a constant shift -> cancels in softmax) ----
    const int wid = tid >> 6;
    float lv = (tid < LL) ? s_logit[tid] : -INFINITY;
    {
        float mx = waveMax(lv);
        if ((tid & 63) == 0) s_red[wid] = mx;
        __syncthreads();
        if (tid == 0) {
            float g = s_red[0];
            #pragma unroll
            for (int w = 1; w < 8; ++w) g = fmaxf(g, s_red[w]);
            s_red[8] = g;
        }
        __syncthreads();
    }
    const float gmax = s_red[8];
    __syncthreads();
    float ex = (tid < LL) ? __expf(lv - gmax) : 0.f;
    {
        float s = waveSum(ex);
        if ((tid & 63) == 0) s_red[wid] = s;
        __syncthreads();
        if (tid == 0) {
            float g = 0.f;
            #pragma unroll
            for (int w = 0; w < 8; ++w) g += s_red[w];
            s_red[8] = g;
        }
        __syncthreads();
    }
    const float inv = 1.f / s_red[8];
    if (tid < LL) s_attn[tid] = ex * inv;
    __syncthreads();

    // ---- out[b] = user + sum_l attn[l] * item_emb[item_ids[b,l]]  (fp32) ----
    {
        const int e = tid & (EE - 1);
        const int g = tid >> 7;            // 0..3, each covers 50 l's
        float acc = 0.f;
        const int lstart = g * (LL / 4);
        for (int l = lstart; l < lstart + LL / 4; ++l) {
            const float a  = s_attn[l];
            const int  id  = item_ids[(size_t)b * LL + l];
            acc += a * item_emb[(size_t)id * EE + e];
        }
        s_part[g][e] = acc;
        __syncthreads();
        if (tid < EE)
            out[(size_t)b * EE + tid] = s_user[tid] + s_part[0][tid] + s_part[1][tid]
                                      + s_part[2][tid] + s_part[3][tid];
    }
}

extern "C" void kernel_launch(void* const* d_in, const int* in_sizes, int n_in,
                              void* d_out, int out_size, void* d_ws, size_t ws_size,
                              hipStream_t stream) {
    const int*   user_ids = (const int*)  d_in[0];
    const int*   item_ids = (const int*)  d_in[1];
    const float* features = (const float*)d_in[2];
    const float* user_emb = (const float*)d_in[3];
    const float* item_emb = (const float*)d_in[4];
    const float* feat_w1  = (const float*)d_in[5];
    const float* feat_b1  = (const float*)d_in[6];
    const float* feat_w2  = (const float*)d_in[7];
    const float* feat_b2  = (const float*)d_in[8];
    const float* w1       = (const float*)d_in[9];
    const float* b1       = (const float*)d_in[10];
    const float* w2       = (const float*)d_in[11];
    const float* b2       = (const float*)d_in[12];
    float* out = (float*)d_out;

    usernet_mfma<<<BB, NTHREADS, 0, stream>>>(user_ids, item_ids, features,
                                              user_emb, item_emb,
                                              feat_w1, feat_b1, feat_w2, feat_b2,
                                              w1, b1, w2, b2, out);
}